// Round 11
// baseline (52.209 us; speedup 1.0000x reference)
//
#include <hip/hip_runtime.h>
#include <math.h>

#define BINS 10
#define NCLS 1000
#define EPSV 1e-8f
#define RPW  16                     // rows per wave
#define RPB  (4 * RPW)              // rows per block (4 waves) = 64
#define NPH  5                      // phase buffers -> prefetch distance 4

// Full-wave (64-lane) sum via DPP: 6 dependent VALU adds (~50 cy) instead of
// 6 ds_bpermute (~720 cy). Valid total lands in lane 63.
__device__ __forceinline__ float dpp_reduce_add_lane63(float x) {
    int t;
    t = __builtin_amdgcn_update_dpp(0, __float_as_int(x), 0x111, 0xF, 0xF, true); x += __int_as_float(t); // row_shr:1
    t = __builtin_amdgcn_update_dpp(0, __float_as_int(x), 0x112, 0xF, 0xF, true); x += __int_as_float(t); // row_shr:2
    t = __builtin_amdgcn_update_dpp(0, __float_as_int(x), 0x114, 0xF, 0xF, true); x += __int_as_float(t); // row_shr:4
    t = __builtin_amdgcn_update_dpp(0, __float_as_int(x), 0x118, 0xF, 0xF, true); x += __int_as_float(t); // row_shr:8
    t = __builtin_amdgcn_update_dpp(0, __float_as_int(x), 0x142, 0xF, 0xF, true); x += __int_as_float(t); // row_bcast:15
    t = __builtin_amdgcn_update_dpp(0, __float_as_int(x), 0x143, 0xF, 0xF, true); x += __int_as_float(t); // row_bcast:31
    return x; // lane 63 holds the full 64-lane sum
}

// Tree-shaped sum of exp over 16 values (depth 4).
__device__ __forceinline__ float exp16_sum(const float4& v0, const float4& v1,
                                           const float4& v2, const float4& v3) {
    float a0 = __expf(v0.x) + __expf(v0.y), a1 = __expf(v0.z) + __expf(v0.w);
    float a2 = __expf(v1.x) + __expf(v1.y), a3 = __expf(v1.z) + __expf(v1.w);
    float a4 = __expf(v2.x) + __expf(v2.y), a5 = __expf(v2.z) + __expf(v2.w);
    float a6 = __expf(v3.x) + __expf(v3.y), a7 = __expf(v3.z) + __expf(v3.w);
    float b0 = a0 + a1, b1 = a2 + a3, b2 = a4 + a5, b3 = a6 + a7;
    return (b0 + b1) + (b2 + b3);
}

// R5 main loop deepened: 1 row/stage, NPH=5 register phases, prefetch
// distance 4 (covers ~1000cy >= ~900cy HBM miss latency; depth 3 covered
// only ~700cy -> per-stage vmcnt stall, 5.6 of 6.3 TB/s). All phase indices
// compile-time (full unroll, k%5) -> no scratch. VGPR ~117 < 128 keeps
// 4 blocks/CU. No fused tail (R7/R8: collapses regalloc to 64 VGPR).
// Partials stored SoA: pcnt[b*nblk + blk] for coalesced pass2 reads.
template<bool EXACT>
__global__ __launch_bounds__(256) void ghmc_pass1(
    const float* __restrict__ pred,
    const int*   __restrict__ target,
    int*   __restrict__ pcnt,
    float* __restrict__ psum,
    int nrows, int nblk)
{
    __shared__ int   s_cnt[BINS];
    __shared__ float s_sum[BINS];
    if (threadIdx.x < BINS) { s_cnt[threadIdx.x] = 0; s_sum[threadIdx.x] = 0.0f; }
    __syncthreads();

    const int lane = threadIdx.x & 63;
    const int wv   = threadIdx.x >> 6;
    const int base = blockIdx.x * RPB + wv * RPW;   // wave owns RPW consecutive rows
    const float NEG = -INFINITY;

    // Preload targets (wave-uniform addresses -> scalar loads).
    int tgt[RPW];
    #pragma unroll
    for (int k = 0; k < RPW; ++k)
        tgt[k] = target[EXACT ? (base + k) : min(base + k, nrows - 1)];

    float4 C0[NPH], C1[NPH], C2[NPH], C3[NPH];
    float  pt[NPH];

#define LOADK(kk, pp) do {                                                    \
    const int r_ = EXACT ? (base + (kk)) : min(base + (kk), nrows - 1);       \
    const float4* rp_ = (const float4*)(pred + (size_t)r_ * NCLS);            \
    C0[pp] = rp_[lane]; C1[pp] = rp_[lane + 64]; C2[pp] = rp_[lane + 128];    \
    if (lane < 58) C3[pp] = rp_[lane + 192];                                  \
    else           C3[pp] = make_float4(NEG, NEG, NEG, NEG);                  \
    pt[pp] = pred[(size_t)r_ * NCLS + tgt[kk]];                               \
} while (0)

    // prologue: 4 batches in flight
    LOADK(0, 0);  LOADK(1, 1);  LOADK(2, 2);  LOADK(3, 3);

    #pragma unroll
    for (int k = 0; k < RPW; ++k) {
        const int p = k % NPH;
        if (k < RPW - 4) LOADK(k + 4, (k + 4) % NPH);   // keep 4 outstanding

        float s = exp16_sum(C0[p], C1[p], C2[p], C3[p]);
        s = dpp_reduce_add_lane63(s);

        if (lane == 63 && (EXACT || base + k < nrows)) {
            const float loss = -pt[p] + __logf(s + EPSV);
            const float g = 1.0f - __expf(pt[p]) / s;
            int b = (int)floorf(g * 10.0f);
            b = min(max(b, 0), BINS - 1);
            atomicAdd(&s_cnt[b], 1);
            atomicAdd(&s_sum[b], loss);
        }
    }
#undef LOADK

    __syncthreads();
    if (threadIdx.x < BINS) {   // SoA slot: full overwrite, deterministic
        pcnt[threadIdx.x * nblk + blockIdx.x] = s_cnt[threadIdx.x];
        psum[threadIdx.x * nblk + blockIdx.x] = s_sum[threadIdx.x];
    }
}

// Pass 2: reduce BINS x nblk SoA partials (coalesced int4/float4 loads),
// then combine: out = sum_b (loss_sum[b] / counts[b]) / n_nonempty
__global__ __launch_bounds__(256) void ghmc_pass2(
    const int* __restrict__ pcnt,
    const float* __restrict__ psum,
    float* __restrict__ out, int nblk)
{
    const int lane = threadIdx.x & 63;
    const int wv   = threadIdx.x >> 6;

    float cnt[BINS], sum[BINS];
    #pragma unroll
    for (int b = 0; b < BINS; ++b) { cnt[b] = 0.0f; sum[b] = 0.0f; }

    if ((nblk & 3) == 0) {
        for (int i = threadIdx.x * 4; i < nblk; i += 1024) {
            #pragma unroll
            for (int b = 0; b < BINS; ++b) {
                const int4   c4 = *(const int4*)  (pcnt + (size_t)b * nblk + i);
                const float4 s4 = *(const float4*)(psum + (size_t)b * nblk + i);
                cnt[b] += (float)(c4.x + c4.y + c4.z + c4.w); // counts <= 65536: exact in f32
                sum[b] += (s4.x + s4.y) + (s4.z + s4.w);
            }
        }
    } else {
        for (int i = threadIdx.x; i < nblk; i += 256) {
            #pragma unroll
            for (int b = 0; b < BINS; ++b) {
                cnt[b] += (float)pcnt[(size_t)b * nblk + i];
                sum[b] += psum[(size_t)b * nblk + i];
            }
        }
    }

    __shared__ float sc[4][BINS], ss[4][BINS];
    #pragma unroll
    for (int b = 0; b < BINS; ++b) {
        const float c = dpp_reduce_add_lane63(cnt[b]);
        const float s = dpp_reduce_add_lane63(sum[b]);
        if (lane == 63) { sc[wv][b] = c; ss[wv][b] = s; }
    }
    __syncthreads();

    if (threadIdx.x == 0) {
        int n = 0;
        float acc = 0.0f;
        for (int b = 0; b < BINS; ++b) {
            const float c = sc[0][b] + sc[1][b] + sc[2][b] + sc[3][b];
            const float s = ss[0][b] + ss[1][b] + ss[2][b] + ss[3][b];
            if (c > 0.0f) { n += 1; acc += s / c; }
        }
        out[0] = acc / (float)max(n, 1);
    }
}

// ---------------- fallback path (tiny ws): atomics + memset ----------------
__global__ __launch_bounds__(256) void ghmc_pass1_atomic(
    const float* __restrict__ pred,
    const int*   __restrict__ target,
    int*   __restrict__ gcnt,
    float* __restrict__ gsum,
    int nrows)
{
    __shared__ int   s_cnt[BINS];
    __shared__ float s_sum[BINS];
    if (threadIdx.x < BINS) { s_cnt[threadIdx.x] = 0; s_sum[threadIdx.x] = 0.0f; }
    __syncthreads();

    const int lane = threadIdx.x & 63;
    const int wv   = threadIdx.x >> 6;
    const int base = blockIdx.x * RPB + wv * RPW;
    const float NEG = -INFINITY;

    int tgt[RPW];
    #pragma unroll
    for (int k = 0; k < RPW; ++k) tgt[k] = target[min(base + k, nrows - 1)];

    float4 C0[NPH], C1[NPH], C2[NPH], C3[NPH];
    float  pt[NPH];

#define LOADK(kk, pp) do {                                                    \
    const int r_ = min(base + (kk), nrows - 1);                               \
    const float4* rp_ = (const float4*)(pred + (size_t)r_ * NCLS);            \
    C0[pp] = rp_[lane]; C1[pp] = rp_[lane + 64]; C2[pp] = rp_[lane + 128];    \
    if (lane < 58) C3[pp] = rp_[lane + 192];                                  \
    else           C3[pp] = make_float4(NEG, NEG, NEG, NEG);                  \
    pt[pp] = pred[(size_t)r_ * NCLS + tgt[kk]];                               \
} while (0)

    LOADK(0, 0);  LOADK(1, 1);  LOADK(2, 2);  LOADK(3, 3);

    #pragma unroll
    for (int k = 0; k < RPW; ++k) {
        const int p = k % NPH;
        if (k < RPW - 4) LOADK(k + 4, (k + 4) % NPH);

        float s = exp16_sum(C0[p], C1[p], C2[p], C3[p]);
        s = dpp_reduce_add_lane63(s);

        if (lane == 63 && base + k < nrows) {
            const float loss = -pt[p] + __logf(s + EPSV);
            const float g = 1.0f - __expf(pt[p]) / s;
            int b = (int)floorf(g * 10.0f);
            b = min(max(b, 0), BINS - 1);
            atomicAdd(&s_cnt[b], 1);
            atomicAdd(&s_sum[b], loss);
        }
    }
#undef LOADK

    __syncthreads();
    if (threadIdx.x < BINS && s_cnt[threadIdx.x] > 0) {
        atomicAdd(&gcnt[threadIdx.x], s_cnt[threadIdx.x]);
        atomicAdd(&gsum[threadIdx.x], s_sum[threadIdx.x]);
    }
}

__global__ void ghmc_pass2_small(const int* __restrict__ gcnt,
                                 const float* __restrict__ gsum,
                                 float* __restrict__ out)
{
    if (threadIdx.x == 0 && blockIdx.x == 0) {
        int n = 0;
        float acc = 0.0f;
        for (int b = 0; b < BINS; ++b) {
            if (gcnt[b] > 0) { n += 1; acc += gsum[b] / (float)gcnt[b]; }
        }
        out[0] = acc / (float)max(n, 1);
    }
}

extern "C" void kernel_launch(void* const* d_in, const int* in_sizes, int n_in,
                              void* d_out, int out_size, void* d_ws, size_t ws_size,
                              hipStream_t stream)
{
    const float* pred   = (const float*)d_in[0];
    const int*   target = (const int*)d_in[1];
    const int nrows  = in_sizes[1];                  // 65536
    const int blocks = (nrows + RPB - 1) / RPB;      // 1024

    const size_t part_bytes = (((size_t)blocks * BINS * sizeof(int)) + 63) & ~(size_t)63;
    const size_t need = 2 * part_bytes;              // pcnt | psum (SoA)

    if (ws_size >= need) {
        int*   pcnt = (int*)d_ws;
        float* psum = (float*)((char*)d_ws + part_bytes);
        if (nrows % RPB == 0)
            ghmc_pass1<true><<<blocks, 256, 0, stream>>>(pred, target, pcnt, psum,
                                                         nrows, blocks);
        else
            ghmc_pass1<false><<<blocks, 256, 0, stream>>>(pred, target, pcnt, psum,
                                                          nrows, blocks);
        ghmc_pass2<<<1, 256, 0, stream>>>(pcnt, psum, (float*)d_out, blocks);
    } else {
        int*   gcnt = (int*)d_ws;
        float* gsum = (float*)((char*)d_ws + 64);
        hipMemsetAsync(d_ws, 0, 128, stream);
        ghmc_pass1_atomic<<<blocks, 256, 0, stream>>>(pred, target, gcnt, gsum, nrows);
        ghmc_pass2_small<<<1, 64, 0, stream>>>(gcnt, gsum, (float*)d_out);
    }
}

// Round 12
// 51.780 us; speedup vs baseline: 1.0083x; 1.0083x over previous
//
#include <hip/hip_runtime.h>
#include <math.h>

#define BINS 10
#define NCLS 1000
#define EPSV 1e-8f
#define RPW  16                     // rows per wave (best measured: R5)
#define RPB  (4 * RPW)              // rows per block (4 waves) = 64
#define NPH  4                      // phase buffers -> prefetch distance 3 (best measured)

// Full-wave (64-lane) sum via DPP: 6 dependent VALU adds (~50 cy) instead of
// 6 ds_bpermute (~720 cy). Valid total lands in lane 63.
__device__ __forceinline__ float dpp_reduce_add_lane63(float x) {
    int t;
    t = __builtin_amdgcn_update_dpp(0, __float_as_int(x), 0x111, 0xF, 0xF, true); x += __int_as_float(t); // row_shr:1
    t = __builtin_amdgcn_update_dpp(0, __float_as_int(x), 0x112, 0xF, 0xF, true); x += __int_as_float(t); // row_shr:2
    t = __builtin_amdgcn_update_dpp(0, __float_as_int(x), 0x114, 0xF, 0xF, true); x += __int_as_float(t); // row_shr:4
    t = __builtin_amdgcn_update_dpp(0, __float_as_int(x), 0x118, 0xF, 0xF, true); x += __int_as_float(t); // row_shr:8
    t = __builtin_amdgcn_update_dpp(0, __float_as_int(x), 0x142, 0xF, 0xF, true); x += __int_as_float(t); // row_bcast:15
    t = __builtin_amdgcn_update_dpp(0, __float_as_int(x), 0x143, 0xF, 0xF, true); x += __int_as_float(t); // row_bcast:31
    return x; // lane 63 holds the full 64-lane sum
}

// Tree-shaped sum of exp over 16 values (depth 4).
__device__ __forceinline__ float exp16_sum(const float4& v0, const float4& v1,
                                           const float4& v2, const float4& v3) {
    float a0 = __expf(v0.x) + __expf(v0.y), a1 = __expf(v0.z) + __expf(v0.w);
    float a2 = __expf(v1.x) + __expf(v1.y), a3 = __expf(v1.z) + __expf(v1.w);
    float a4 = __expf(v2.x) + __expf(v2.y), a5 = __expf(v2.z) + __expf(v2.w);
    float a6 = __expf(v3.x) + __expf(v3.y), a7 = __expf(v3.z) + __expf(v3.w);
    float b0 = a0 + a1, b1 = a2 + a3, b2 = a4 + a5, b3 = a6 + a7;
    return (b0 + b1) + (b2 + b3);
}

// FINAL (best-measured config, R5 geometry + R10 refinements):
// 1 row/stage, 4 register phases, 3 batches in flight/wave, 1024 blocks x
// 64 rows. Probed and rejected with counters: 2048x32 (R9: drain fraction),
// fused last-block tail (R7/R8: regalloc collapse to 64 VGPR, +60%),
// prefetch depth 4 (R11: null — pred is largely L3-resident so depth 3
// already covers effective latency). Pass1 ~5.8 TB/s = 92% of the measured
// float4-copy ceiling (6.29 TB/s).
template<bool EXACT>
__global__ __launch_bounds__(256) void ghmc_pass1(
    const float* __restrict__ pred,
    const int*   __restrict__ target,
    int*   __restrict__ pcnt,
    float* __restrict__ psum,
    int nrows, int nblk)
{
    __shared__ int   s_cnt[BINS];
    __shared__ float s_sum[BINS];
    if (threadIdx.x < BINS) { s_cnt[threadIdx.x] = 0; s_sum[threadIdx.x] = 0.0f; }
    __syncthreads();

    const int lane = threadIdx.x & 63;
    const int wv   = threadIdx.x >> 6;
    const int base = blockIdx.x * RPB + wv * RPW;   // wave owns RPW consecutive rows
    const float NEG = -INFINITY;

    // Preload targets (wave-uniform addresses -> scalar loads).
    int tgt[RPW];
    #pragma unroll
    for (int k = 0; k < RPW; ++k)
        tgt[k] = target[EXACT ? (base + k) : min(base + k, nrows - 1)];

    float4 C0[NPH], C1[NPH], C2[NPH], C3[NPH];
    float  pt[NPH];

#define LOADK(kk, pp) do {                                                    \
    const int r_ = EXACT ? (base + (kk)) : min(base + (kk), nrows - 1);       \
    const float4* rp_ = (const float4*)(pred + (size_t)r_ * NCLS);            \
    C0[pp] = rp_[lane]; C1[pp] = rp_[lane + 64]; C2[pp] = rp_[lane + 128];    \
    if (lane < 58) C3[pp] = rp_[lane + 192];                                  \
    else           C3[pp] = make_float4(NEG, NEG, NEG, NEG);                  \
    pt[pp] = pred[(size_t)r_ * NCLS + tgt[kk]];                               \
} while (0)

    LOADK(0, 0);  LOADK(1, 1);  LOADK(2, 2);   // prologue: 3 batches in flight

    #pragma unroll
    for (int k = 0; k < RPW; ++k) {
        const int p = k & 3;
        if (k < RPW - 3) LOADK(k + 3, (k + 3) & 3);   // keep 3 outstanding

        float s = exp16_sum(C0[p], C1[p], C2[p], C3[p]);
        s = dpp_reduce_add_lane63(s);

        if (lane == 63 && (EXACT || base + k < nrows)) {
            const float loss = -pt[p] + __logf(s + EPSV);
            const float g = 1.0f - __expf(pt[p]) / s;
            int b = (int)floorf(g * 10.0f);
            b = min(max(b, 0), BINS - 1);
            atomicAdd(&s_cnt[b], 1);
            atomicAdd(&s_sum[b], loss);
        }
    }
#undef LOADK

    __syncthreads();
    if (threadIdx.x < BINS) {   // SoA slot: full overwrite, deterministic
        pcnt[threadIdx.x * nblk + blockIdx.x] = s_cnt[threadIdx.x];
        psum[threadIdx.x * nblk + blockIdx.x] = s_sum[threadIdx.x];
    }
}

// Pass 2: reduce BINS x nblk SoA partials (coalesced int4/float4 loads),
// then combine: out = sum_b (loss_sum[b] / counts[b]) / n_nonempty
__global__ __launch_bounds__(256) void ghmc_pass2(
    const int* __restrict__ pcnt,
    const float* __restrict__ psum,
    float* __restrict__ out, int nblk)
{
    const int lane = threadIdx.x & 63;
    const int wv   = threadIdx.x >> 6;

    float cnt[BINS], sum[BINS];
    #pragma unroll
    for (int b = 0; b < BINS; ++b) { cnt[b] = 0.0f; sum[b] = 0.0f; }

    if ((nblk & 3) == 0) {
        for (int i = threadIdx.x * 4; i < nblk; i += 1024) {
            #pragma unroll
            for (int b = 0; b < BINS; ++b) {
                const int4   c4 = *(const int4*)  (pcnt + (size_t)b * nblk + i);
                const float4 s4 = *(const float4*)(psum + (size_t)b * nblk + i);
                cnt[b] += (float)(c4.x + c4.y + c4.z + c4.w); // counts <= 65536: exact in f32
                sum[b] += (s4.x + s4.y) + (s4.z + s4.w);
            }
        }
    } else {
        for (int i = threadIdx.x; i < nblk; i += 256) {
            #pragma unroll
            for (int b = 0; b < BINS; ++b) {
                cnt[b] += (float)pcnt[(size_t)b * nblk + i];
                sum[b] += psum[(size_t)b * nblk + i];
            }
        }
    }

    __shared__ float sc[4][BINS], ss[4][BINS];
    #pragma unroll
    for (int b = 0; b < BINS; ++b) {
        const float c = dpp_reduce_add_lane63(cnt[b]);
        const float s = dpp_reduce_add_lane63(sum[b]);
        if (lane == 63) { sc[wv][b] = c; ss[wv][b] = s; }
    }
    __syncthreads();

    if (threadIdx.x == 0) {
        int n = 0;
        float acc = 0.0f;
        for (int b = 0; b < BINS; ++b) {
            const float c = sc[0][b] + sc[1][b] + sc[2][b] + sc[3][b];
            const float s = ss[0][b] + ss[1][b] + ss[2][b] + ss[3][b];
            if (c > 0.0f) { n += 1; acc += s / c; }
        }
        out[0] = acc / (float)max(n, 1);
    }
}

// ---------------- fallback path (tiny ws): atomics + memset ----------------
__global__ __launch_bounds__(256) void ghmc_pass1_atomic(
    const float* __restrict__ pred,
    const int*   __restrict__ target,
    int*   __restrict__ gcnt,
    float* __restrict__ gsum,
    int nrows)
{
    __shared__ int   s_cnt[BINS];
    __shared__ float s_sum[BINS];
    if (threadIdx.x < BINS) { s_cnt[threadIdx.x] = 0; s_sum[threadIdx.x] = 0.0f; }
    __syncthreads();

    const int lane = threadIdx.x & 63;
    const int wv   = threadIdx.x >> 6;
    const int base = blockIdx.x * RPB + wv * RPW;
    const float NEG = -INFINITY;

    int tgt[RPW];
    #pragma unroll
    for (int k = 0; k < RPW; ++k) tgt[k] = target[min(base + k, nrows - 1)];

    float4 C0[NPH], C1[NPH], C2[NPH], C3[NPH];
    float  pt[NPH];

#define LOADK(kk, pp) do {                                                    \
    const int r_ = min(base + (kk), nrows - 1);                               \
    const float4* rp_ = (const float4*)(pred + (size_t)r_ * NCLS);            \
    C0[pp] = rp_[lane]; C1[pp] = rp_[lane + 64]; C2[pp] = rp_[lane + 128];    \
    if (lane < 58) C3[pp] = rp_[lane + 192];                                  \
    else           C3[pp] = make_float4(NEG, NEG, NEG, NEG);                  \
    pt[pp] = pred[(size_t)r_ * NCLS + tgt[kk]];                               \
} while (0)

    LOADK(0, 0);  LOADK(1, 1);  LOADK(2, 2);

    #pragma unroll
    for (int k = 0; k < RPW; ++k) {
        const int p = k & 3;
        if (k < RPW - 3) LOADK(k + 3, (k + 3) & 3);

        float s = exp16_sum(C0[p], C1[p], C2[p], C3[p]);
        s = dpp_reduce_add_lane63(s);

        if (lane == 63 && base + k < nrows) {
            const float loss = -pt[p] + __logf(s + EPSV);
            const float g = 1.0f - __expf(pt[p]) / s;
            int b = (int)floorf(g * 10.0f);
            b = min(max(b, 0), BINS - 1);
            atomicAdd(&s_cnt[b], 1);
            atomicAdd(&s_sum[b], loss);
        }
    }
#undef LOADK

    __syncthreads();
    if (threadIdx.x < BINS && s_cnt[threadIdx.x] > 0) {
        atomicAdd(&gcnt[threadIdx.x], s_cnt[threadIdx.x]);
        atomicAdd(&gsum[threadIdx.x], s_sum[threadIdx.x]);
    }
}

__global__ void ghmc_pass2_small(const int* __restrict__ gcnt,
                                 const float* __restrict__ gsum,
                                 float* __restrict__ out)
{
    if (threadIdx.x == 0 && blockIdx.x == 0) {
        int n = 0;
        float acc = 0.0f;
        for (int b = 0; b < BINS; ++b) {
            if (gcnt[b] > 0) { n += 1; acc += gsum[b] / (float)gcnt[b]; }
        }
        out[0] = acc / (float)max(n, 1);
    }
}

extern "C" void kernel_launch(void* const* d_in, const int* in_sizes, int n_in,
                              void* d_out, int out_size, void* d_ws, size_t ws_size,
                              hipStream_t stream)
{
    const float* pred   = (const float*)d_in[0];
    const int*   target = (const int*)d_in[1];
    const int nrows  = in_sizes[1];                  // 65536
    const int blocks = (nrows + RPB - 1) / RPB;      // 1024

    const size_t part_bytes = (((size_t)blocks * BINS * sizeof(int)) + 63) & ~(size_t)63;
    const size_t need = 2 * part_bytes;              // pcnt | psum (SoA)

    if (ws_size >= need) {
        int*   pcnt = (int*)d_ws;
        float* psum = (float*)((char*)d_ws + part_bytes);
        if (nrows % RPB == 0)
            ghmc_pass1<true><<<blocks, 256, 0, stream>>>(pred, target, pcnt, psum,
                                                         nrows, blocks);
        else
            ghmc_pass1<false><<<blocks, 256, 0, stream>>>(pred, target, pcnt, psum,
                                                          nrows, blocks);
        ghmc_pass2<<<1, 256, 0, stream>>>(pcnt, psum, (float*)d_out, blocks);
    } else {
        int*   gcnt = (int*)d_ws;
        float* gsum = (float*)((char*)d_ws + 64);
        hipMemsetAsync(d_ws, 0, 128, stream);
        ghmc_pass1_atomic<<<blocks, 256, 0, stream>>>(pred, target, gcnt, gsum, nrows);
        ghmc_pass2_small<<<1, 64, 0, stream>>>(gcnt, gsum, (float*)d_out);
    }
}